// Round 1
// baseline (264.190 us; speedup 1.0000x reference)
//
#include <hip/hip_runtime.h>
#include <hip/hip_bf16.h>

// Embed3D: out[n,l, c*40 + k*2 + {0,1}] = {sin,cos}(x[n,l,1+c] * div_term[k])
// N=64, L=8192, D_MODEL=120, 20 frequencies, 3 channels.
// Pure write-BW-bound expand: one thread per output float4 (2 sin/cos pairs).

__global__ __launch_bounds__(256) void Embed3D_kernel(
    const float* __restrict__ x,        // (64*8192, 4)
    const float* __restrict__ div_term, // (20,)
    float* __restrict__ out,            // (64*8192, 120)
    int n_quads)                        // total float4 outputs = 64*8192*30
{
    int q = blockIdx.x * blockDim.x + threadIdx.x;
    if (q >= n_quads) return;

    int pos_idx = q / 30;               // which (n,l) position
    int rem     = q - pos_idx * 30;     // 0..29: which float4 within the 120
    int c       = rem / 10;             // channel 0..2  (x channel 1+c)
    int k0      = rem * 2 - c * 20;     // frequency index of first pair (even, <=18)

    float p  = x[pos_idx * 4 + 1 + c];  // broadcast across 30 threads -> L1 hit
    float d0 = div_term[k0];
    float d1 = div_term[k0 + 1];

    float s0, c0, s1, c1;
    __sincosf(p * d0, &s0, &c0);        // args < 1 rad; hw sin/cos plenty accurate
    __sincosf(p * d1, &s1, &c1);

    float4 v = make_float4(s0, c0, s1, c1);
    reinterpret_cast<float4*>(out)[q] = v;
}

extern "C" void kernel_launch(void* const* d_in, const int* in_sizes, int n_in,
                              void* d_out, int out_size, void* d_ws, size_t ws_size,
                              hipStream_t stream) {
    const float* x        = (const float*)d_in[0];  // 64*8192*4 floats
    const float* div_term = (const float*)d_in[1];  // 20 floats
    float* out            = (float*)d_out;          // 64*8192*120 floats

    int n_quads = out_size / 4;                     // 15,728,640
    int block = 256;
    int grid  = (n_quads + block - 1) / block;      // 61,440 blocks
    Embed3D_kernel<<<grid, block, 0, stream>>>(x, div_term, out, n_quads);
}

// Round 2
// 263.571 us; speedup vs baseline: 1.0024x; 1.0024x over previous
//
#include <hip/hip_runtime.h>
#include <hip/hip_bf16.h>

// Embed3D: out[n,l, c*40 + 2k + {0,1}] = {sin,cos}(x[n,l,1+c] * div_term[k])
// N=64, L=8192 -> 524288 positions; 20 freqs x 3 channels -> 120 floats/pos.
// One thread per output float4 (one sin/cos pair x2). Block = (30, 32):
//   threadIdx.x = rem (which float4 of the 30 per position) -> no div/mod
//   960 threads = exactly 15 waves, writes 15 KB contiguous per block.

constexpr float INV_2PI = 0.15915494309189535f;  // hw v_sin/v_cos take revolutions

__global__ __launch_bounds__(960) void Embed3D_kernel(
    const float4* __restrict__ x4,       // (524288) float4: [.,p1,p2,p3]
    const float2* __restrict__ div2,     // (10) float2 pairs of div_term
    float4* __restrict__ out4)           // (524288*30) float4
{
    const int rem = threadIdx.x;                         // 0..29
    const int pos = blockIdx.x * 32 + threadIdx.y;       // 0..524287

    // c = rem/10 for rem<32 via tiny magic mul (no v_mul_lo needed)
    const int c  = (rem * 205) >> 11;                    // 0,1,2
    const int kp = rem - 10 * c;                         // pair index 0..9

    const float4 xv = x4[pos];                           // L1 broadcast across lanes
    const float p   = (c == 0) ? xv.y : (c == 1) ? xv.z : xv.w;

    const float2 d = div2[kp];                           // div_term[2kp], div_term[2kp+1]
    const float r0 = p * d.x * INV_2PI;                  // revolutions
    const float r1 = p * d.y * INV_2PI;

    float4 v;
    v.x = __builtin_amdgcn_sinf(r0);
    v.y = __builtin_amdgcn_cosf(r0);
    v.z = __builtin_amdgcn_sinf(r1);
    v.w = __builtin_amdgcn_cosf(r1);

    out4[pos * 30 + rem] = v;                            // contiguous across block
}

extern "C" void kernel_launch(void* const* d_in, const int* in_sizes, int n_in,
                              void* d_out, int out_size, void* d_ws, size_t ws_size,
                              hipStream_t stream) {
    const float4* x4   = (const float4*)d_in[0];   // 524288 x float4
    const float2* div2 = (const float2*)d_in[1];   // 10 x float2
    float4* out4       = (float4*)d_out;           // 15,728,640 x float4

    const int positions = in_sizes[0] / 4;         // 524288
    dim3 block(30, 32);                            // 960 = 15 waves
    dim3 grid(positions / 32);                     // 16384 blocks
    Embed3D_kernel<<<grid, block, 0, stream>>>(x4, div2, out4);
}

// Round 3
// 257.465 us; speedup vs baseline: 1.0261x; 1.0237x over previous
//
#include <hip/hip_runtime.h>
#include <hip/hip_bf16.h>

// Embed3D: out[n,l, c*40 + 2k + {0,1}] = {sin,cos}(x[n,l,1+c] * div_term[k])
// 524288 positions x 120 floats. One thread per (rem, position-set):
// rem = which of the 30 float4s per position; each thread handles PPT=8
// positions (stride 32) -> 8 independent 16-B stores per thread, amortizing
// wave setup/turnover (R2 showed 1-store-per-thread plateaus at ~2.5 TB/s).
// Block (30,32) = 15 waves writes a fully contiguous 120-KB span.

constexpr float INV_2PI = 0.15915494309189535f;  // hw v_sin/v_cos take revolutions
constexpr int PPT = 8;                           // positions per thread

__global__ __launch_bounds__(960) void Embed3D_kernel(
    const float4* __restrict__ x4,       // (524288) float4: [.,p1,p2,p3]
    const float2* __restrict__ div2,     // (10) float2 pairs of div_term
    float4* __restrict__ out4)           // (524288*30) float4
{
    const int rem = threadIdx.x;                         // 0..29
    const int ty  = threadIdx.y;                         // 0..31

    const int c  = (rem * 205) >> 11;                    // rem/10: 0,1,2
    const int kp = rem - 10 * c;                         // pair index 0..9

    const float2 d  = div2[kp];
    const float m0  = d.x * INV_2PI;                     // fold revolutions scale
    const float m1  = d.y * INV_2PI;

    const int base = blockIdx.x * (32 * PPT) + ty;       // first position

    // Issue all loads first (ILP; 8 outstanding loads per lane)
    float p[PPT];
#pragma unroll
    for (int i = 0; i < PPT; ++i) {
        const float4 xv = x4[base + 32 * i];             // L1 broadcast
        p[i] = (c == 0) ? xv.y : (c == 1) ? xv.z : xv.w;
    }

#pragma unroll
    for (int i = 0; i < PPT; ++i) {
        const float r0 = p[i] * m0;
        const float r1 = p[i] * m1;
        float4 v;
        v.x = __builtin_amdgcn_sinf(r0);
        v.y = __builtin_amdgcn_cosf(r0);
        v.z = __builtin_amdgcn_sinf(r1);
        v.w = __builtin_amdgcn_cosf(r1);
        out4[(base + 32 * i) * 30 + rem] = v;            // wave: 1 KB contiguous
    }
}

extern "C" void kernel_launch(void* const* d_in, const int* in_sizes, int n_in,
                              void* d_out, int out_size, void* d_ws, size_t ws_size,
                              hipStream_t stream) {
    const float4* x4   = (const float4*)d_in[0];   // 524288 x float4
    const float2* div2 = (const float2*)d_in[1];   // 10 x float2
    float4* out4       = (float4*)d_out;           // 15,728,640 x float4

    const int positions = in_sizes[0] / 4;         // 524288
    dim3 block(30, 32);                            // 960 = 15 waves
    dim3 grid(positions / (32 * PPT));             // 2048 blocks
    Embed3D_kernel<<<grid, block, 0, stream>>>(x4, div2, out4);
}